// Round 9
// baseline (82.958 us; speedup 1.0000x reference)
//
#include <hip/hip_runtime.h>
#include <hip/hip_bf16.h>

#define NB 2
#define NH 16
#define NHKV 4
#define GQ 4
#define SQL 2048
#define SKV 2048
#define DH 64
#define QB 32
#define KVBLK 64
#define LDK 72   // vT leading dim (bf16): 144B stride

#define QSCALE (0.125f * 1.44269504f)   // 1/sqrt(D) * log2(e)
#define M2REF  (4.0f * 1.44269504f)     // fixed softmax reference (log2 domain)

typedef __bf16 v8bf  __attribute__((ext_vector_type(8)));
typedef __bf16 v2bf  __attribute__((ext_vector_type(2)));
typedef float  f32x4 __attribute__((ext_vector_type(4)));

__device__ __forceinline__ v8bf cvtbf8(float4 a, float4 b) {
  v8bf t;
  t[0]=(__bf16)a.x; t[1]=(__bf16)a.y; t[2]=(__bf16)a.z; t[3]=(__bf16)a.w;
  t[4]=(__bf16)b.x; t[5]=(__bf16)b.y; t[6]=(__bf16)b.z; t[7]=(__bf16)b.w;
  return t;
}
__device__ __forceinline__ v8bf cvtbf8s(float4 a, float4 b, float sc) {
  v8bf t;
  t[0]=(__bf16)(a.x*sc); t[1]=(__bf16)(a.y*sc); t[2]=(__bf16)(a.z*sc); t[3]=(__bf16)(a.w*sc);
  t[4]=(__bf16)(b.x*sc); t[5]=(__bf16)(b.y*sc); t[6]=(__bf16)(b.z*sc); t[7]=(__bf16)(b.w*sc);
  return t;
}

__global__ __launch_bounds__(64, 4)
void gqa_seg_attn(const float* __restrict__ q,
                  const float* __restrict__ k,
                  const float* __restrict__ v,
                  const int* __restrict__ qseg,
                  const int* __restrict__ kvseg,
                  float* __restrict__ out)
{
  // Wave-private (1 wave per block): no __syncthreads anywhere.
  __shared__ __bf16 vT_lds[DH][LDK];   // [d][kv] transposed V (R1-proven layout)
  __shared__ __bf16 p_lds[QB][LDK];    // P round-trip

  const int l   = threadIdx.x;
  const int l15 = l & 15;
  const int lg  = l >> 4;
  const int qt  = blockIdx.x;
  const int h   = blockIdx.y;
  const int b   = blockIdx.z;
  const int kvh = h / GQ;
  const int q0  = qt * QB;

  const float* qptr   = q + (((size_t)b * NH   + h  ) * SQL) * DH;
  const float* kptr   = k + (((size_t)b * NHKV + kvh) * SKV) * DH;
  const float* vptr   = v + (((size_t)b * NHKV + kvh) * SKV) * DH;
  const int*   qsegb  = qseg  + (size_t)b * SQL;
  const int*   kvsegb = kvseg + (size_t)b * SKV;

  // ---- Q fragments (2 q-subtiles x 2 d-chunks), prescaled (log2e folded in)
  v8bf qfrag[2][2];
  #pragma unroll
  for (int qs = 0; qs < 2; ++qs)
    #pragma unroll
    for (int c = 0; c < 2; ++c) {
      const float* src = qptr + (size_t)(q0 + qs * 16 + l15) * DH + c * 32 + lg * 8;
      qfrag[qs][c] = cvtbf8s(*(const float4*)src, *(const float4*)(src + 4), QSCALE);
    }

  int qsegr[2][4];
  #pragma unroll
  for (int qs = 0; qs < 2; ++qs)
    #pragma unroll
    for (int r = 0; r < 4; ++r)
      qsegr[qs][r] = qsegb[q0 + qs * 16 + lg * 4 + r];

  const int smin = qsegb[q0];
  const int smax = qsegb[q0 + QB - 1];

  // ---- valid KV band (both sides sorted)
  int lo, hi;
  {
    int a = 0, e = SKV;
    while (a < e) { int m = (a + e) >> 1; if (kvsegb[m] <  smin) a = m + 1; else e = m; }
    lo = a;
    a = lo; e = SKV;
    while (a < e) { int m = (a + e) >> 1; if (kvsegb[m] <= smax) a = m + 1; else e = m; }
    hi = a;
  }
  int t0i = lo >> 6;
  int t1i = (hi + KVBLK - 1) >> 6;
  if (hi <= lo) t1i = t0i;

  float l_acc[2][4];
  f32x4 o_acc[2][4];
  #pragma unroll
  for (int qs = 0; qs < 2; ++qs)
    #pragma unroll
    for (int r = 0; r < 4; ++r) { l_acc[qs][r] = 0.f; o_acc[qs][r] = (f32x4){0.f,0.f,0.f,0.f}; }

  // V staging roles: lane stages 2 kv rows (vp*2, vp*2+1), d-half dh0..dh0+31.
  // Paired ds_write_b32: 32 lanes -> 32 distinct banks (conflict-free); halves 2-way (free).
  const int vp  = l & 31;
  const int dh0 = (l >> 5) * 32;

  for (int kt = t0i; kt < t1i; ++kt) {
    const int kv0 = kt * KVBLK;

    int kvs[4];
    #pragma unroll
    for (int n = 0; n < 4; ++n) kvs[n] = kvsegb[kv0 + n * 16 + l15];
    const int tmin = __shfl(kvs[0], 0);
    const int tmax = __shfl(kvs[3], 15);
    if (tmax < smin || tmin > smax) continue;   // wave-uniform tile skip

    // ---- stage V transposed (wave-private): 2 rows x 32 d per lane
    {
      const float* vs0 = vptr + (size_t)(kv0 + 2 * vp) * DH + dh0;
      const float* vs1 = vs0 + DH;
      #pragma unroll
      for (int i = 0; i < 32; i += 4) {
        float4 f0 = *(const float4*)(vs0 + i);
        float4 f1 = *(const float4*)(vs1 + i);
        v2bf w0; w0[0] = (__bf16)f0.x; w0[1] = (__bf16)f1.x;
        v2bf w1; w1[0] = (__bf16)f0.y; w1[1] = (__bf16)f1.y;
        v2bf w2; w2[0] = (__bf16)f0.z; w2[1] = (__bf16)f1.z;
        v2bf w3; w3[0] = (__bf16)f0.w; w3[1] = (__bf16)f1.w;
        *(v2bf*)&vT_lds[dh0 + i + 0][2 * vp] = w0;
        *(v2bf*)&vT_lds[dh0 + i + 1][2 * vp] = w1;
        *(v2bf*)&vT_lds[dh0 + i + 2][2 * vp] = w2;
        *(v2bf*)&vT_lds[dh0 + i + 3][2 * vp] = w3;
      }
    }

    // ---- K fragments direct from global (L2-resident; same fragment layout as R1's LDS path)
    v8bf kbf[4][2];
    #pragma unroll
    for (int n = 0; n < 4; ++n) {
      const float* ks = kptr + (size_t)(kv0 + n * 16 + l15) * DH + lg * 8;
      #pragma unroll
      for (int c = 0; c < 2; ++c)
        kbf[n][c] = cvtbf8(*(const float4*)(ks + c * 32), *(const float4*)(ks + c * 32 + 4));
    }

    // ---- QK^T (C init = -M2REF folds the softmax reference in)
    f32x4 s[2][4];
    __builtin_amdgcn_s_setprio(1);
    #pragma unroll
    for (int qs = 0; qs < 2; ++qs)
      #pragma unroll
      for (int n = 0; n < 4; ++n) {
        s[qs][n] = (f32x4){-M2REF, -M2REF, -M2REF, -M2REF};
        #pragma unroll
        for (int c = 0; c < 2; ++c)
          s[qs][n] = __builtin_amdgcn_mfma_f32_16x16x32_bf16(qfrag[qs][c], kbf[n][c], s[qs][n], 0, 0, 0);
      }
    __builtin_amdgcn_s_setprio(0);

    // ---- mask + exp2 + P write + l accumulate
    #pragma unroll
    for (int qs = 0; qs < 2; ++qs)
      #pragma unroll
      for (int n = 0; n < 4; ++n)
        #pragma unroll
        for (int r = 0; r < 4; ++r) {
          float sv = (kvs[n] == qsegr[qs][r]) ? s[qs][n][r] : -__builtin_inff();
          float pv = __builtin_amdgcn_exp2f(sv);
          l_acc[qs][r] += pv;
          p_lds[qs * 16 + lg * 4 + r][n * 16 + l15] = (__bf16)pv;
        }

    // ---- P fragments (A-operand) + V fragments (B-operand), both R1-proven layouts
    v8bf pa[2][2];
    #pragma unroll
    for (int qs = 0; qs < 2; ++qs)
      #pragma unroll
      for (int c = 0; c < 2; ++c)
        pa[qs][c] = *(const v8bf*)&p_lds[qs * 16 + l15][c * 32 + lg * 8];

    v8bf vbn[4][2];
    #pragma unroll
    for (int t = 0; t < 4; ++t)
      #pragma unroll
      for (int c = 0; c < 2; ++c)
        vbn[t][c] = *(const v8bf*)&vT_lds[t * 16 + l15][c * 32 + lg * 8];

    // ---- PV
    __builtin_amdgcn_s_setprio(1);
    #pragma unroll
    for (int qs = 0; qs < 2; ++qs)
      #pragma unroll
      for (int t = 0; t < 4; ++t)
        #pragma unroll
        for (int c = 0; c < 2; ++c)
          o_acc[qs][t] = __builtin_amdgcn_mfma_f32_16x16x32_bf16(pa[qs][c], vbn[t][c], o_acc[qs][t], 0, 0, 0);
    __builtin_amdgcn_s_setprio(0);
  }

  // ---- epilogue: reduce l over the 16 columns, normalize; empty rows -> 0
  float* outp = out + (((size_t)b * NH + h) * SQL) * DH;
  #pragma unroll
  for (int qs = 0; qs < 2; ++qs)
    #pragma unroll
    for (int r = 0; r < 4; ++r) {
      float x = l_acc[qs][r];
      x += __shfl_xor(x, 1); x += __shfl_xor(x, 2);
      x += __shfl_xor(x, 4); x += __shfl_xor(x, 8);
      float inv = (x > 0.f) ? (1.f / x) : 0.f;
      const size_t row = (size_t)(q0 + qs * 16 + lg * 4 + r) * DH;
      #pragma unroll
      for (int t = 0; t < 4; ++t)
        outp[row + t * 16 + l15] = o_acc[qs][t][r] * inv;
    }
}

extern "C" void kernel_launch(void* const* d_in, const int* in_sizes, int n_in,
                              void* d_out, int out_size, void* d_ws, size_t ws_size,
                              hipStream_t stream) {
  const float* q     = (const float*)d_in[0];
  const float* k     = (const float*)d_in[1];
  const float* v     = (const float*)d_in[2];
  const int*   qseg  = (const int*)d_in[3];
  const int*   kvseg = (const int*)d_in[4];
  float* out = (float*)d_out;

  dim3 grid(SQL / QB, NH, NB);
  dim3 block(64);
  gqa_seg_attn<<<grid, block, 0, stream>>>(q, k, v, qseg, kvseg, out);
}

// Round 10
// 55.455 us; speedup vs baseline: 1.4960x; 1.4960x over previous
//
#include <hip/hip_runtime.h>
#include <hip/hip_bf16.h>

#define NB   2
#define NH   16
#define NHKV 4
#define GQ   4
#define SQL  2048
#define SKV  2048
#define DH   64
#define QBLK 64
#define KVBLK 64
#define LDK  72   // padded leading dim (bf16): 144B stride, rows 16B-aligned
#define NTASK (32 * NH * NB)   // (SQL/QBLK) * NH * NB = 1024
#define GRID  768              // 3 blocks/CU residency ceiling * 256 CU

#define QSCALE (0.125f * 1.44269504f)   // 1/sqrt(D) * log2(e)
#define M2REF  (4.0f * 1.44269504f)     // fixed softmax reference (log2 domain)

typedef __bf16 v8bf  __attribute__((ext_vector_type(8)));
typedef float  f32x4 __attribute__((ext_vector_type(4)));

__global__ void init_counter(unsigned* cnt) { if (threadIdx.x == 0) *cnt = 0u; }

__global__ __launch_bounds__(256, 3)
void gqa_seg_attn(const float* __restrict__ q,
                  const float* __restrict__ k,
                  const float* __restrict__ v,
                  const int* __restrict__ qseg,
                  const int* __restrict__ kvseg,
                  float* __restrict__ out,
                  unsigned* __restrict__ cnt)
{
    __shared__ __bf16 k_lds[2][KVBLK][LDK];   // double-buffered [kv][d]
    __shared__ __bf16 vT_lds[2][DH][LDK];     // double-buffered [d][kv]
    __shared__ __bf16 p_lds[4][16][LDK];      // per-wave P re-layout
    __shared__ int    task_s;

    const int tid  = threadIdx.x;
    const int lane = tid & 63;
    const int w    = tid >> 6;
    const int l15  = lane & 15;
    const int lg   = lane >> 4;
    const int d_a  = lg * 8;

    // staging roles (task-independent)
    const int krow = tid >> 2, kc0 = (tid & 3) * 16;   // K: 16 floats/thread
    const int vcol = tid & 63, vd0 = (tid >> 6) * 16;  // V: 16 floats/thread

    for (;;) {
        if (tid == 0) task_s = atomicAdd(cnt, 1u);
        __syncthreads();
        const int task = task_s;
        __syncthreads();           // task_s consumed before next overwrite
        if (task >= NTASK) break;  // uniform exit

        // decode: consecutive tasks share (h,b) -> K/V slab stays L2-hot
        const int qt = task & 31;
        const int h  = (task >> 5) & 15;
        const int b  = task >> 9;
        const int kvh = h / GQ;
        const int q0  = qt * QBLK;

        const float* qptr   = q + (((size_t)b * NH   + h  ) * SQL) * DH;
        const float* kptr   = k + (((size_t)b * NHKV + kvh) * SKV) * DH;
        const float* vptr   = v + (((size_t)b * NHKV + kvh) * SKV) * DH;
        const int*   qsegb  = qseg  + (size_t)b * SQL;
        const int*   kvsegb = kvseg + (size_t)b * SKV;

        // ---- Q fragments: row (w*16 + l15), prescaled (log2e folded in)
        v8bf qfrag[2];
        {
            const int qrow = q0 + w * 16 + l15;
            for (int c = 0; c < 2; ++c) {
                const float* src = qptr + (size_t)qrow * DH + c * 32 + d_a;
                float4 f0 = *(const float4*)(src);
                float4 f1 = *(const float4*)(src + 4);
                v8bf t;
                t[0] = (__bf16)(f0.x * QSCALE); t[1] = (__bf16)(f0.y * QSCALE);
                t[2] = (__bf16)(f0.z * QSCALE); t[3] = (__bf16)(f0.w * QSCALE);
                t[4] = (__bf16)(f1.x * QSCALE); t[5] = (__bf16)(f1.y * QSCALE);
                t[6] = (__bf16)(f1.z * QSCALE); t[7] = (__bf16)(f1.w * QSCALE);
                qfrag[c] = t;
            }
        }

        const int qrow_c0 = q0 + w * 16 + (lg << 2);
        int qsegr[4];
        for (int r = 0; r < 4; ++r) qsegr[r] = qsegb[qrow_c0 + r];

        const int wsmin = qsegb[q0 + w * 16];
        const int wsmax = qsegb[q0 + w * 16 + 15];

        // ---- block-level valid KV band (both sides sorted)
        const int smin = qsegb[q0];
        const int smax = qsegb[q0 + QBLK - 1];
        int lo, hi;
        {
            int a = 0, e = SKV;
            while (a < e) { int m = (a + e) >> 1; if (kvsegb[m] <  smin) a = m + 1; else e = m; }
            lo = a;
            a = lo; e = SKV;
            while (a < e) { int m = (a + e) >> 1; if (kvsegb[m] <= smax) a = m + 1; else e = m; }
            hi = a;
        }
        int t0i = lo >> 6;
        int t1i = (hi + KVBLK - 1) >> 6;
        if (hi <= lo) t1i = t0i;
        const int nt = t1i - t0i;

        float4 ka[4], va[4];
        int kvs_cur[4], kvs_nxt[4];

        auto issue = [&](int kt) {
            const int kv0 = kt * KVBLK;
            for (int r2 = 0; r2 < 4; ++r2)
                kvs_nxt[r2] = kvsegb[kv0 + r2 * 16 + l15];
            const float* ks = kptr + (size_t)(kv0 + krow) * DH + kc0;
            const float* vs = vptr + (size_t)(kv0 + vcol) * DH + vd0;
            for (int i2 = 0; i2 < 4; ++i2) {
                ka[i2] = *(const float4*)(ks + 4 * i2);
                va[i2] = *(const float4*)(vs + 4 * i2);
            }
        };
        auto commit = [&](int p) {
            v8bf ta, tb;
            ta[0] = (__bf16)ka[0].x; ta[1] = (__bf16)ka[0].y;
            ta[2] = (__bf16)ka[0].z; ta[3] = (__bf16)ka[0].w;
            ta[4] = (__bf16)ka[1].x; ta[5] = (__bf16)ka[1].y;
            ta[6] = (__bf16)ka[1].z; ta[7] = (__bf16)ka[1].w;
            tb[0] = (__bf16)ka[2].x; tb[1] = (__bf16)ka[2].y;
            tb[2] = (__bf16)ka[2].z; tb[3] = (__bf16)ka[2].w;
            tb[4] = (__bf16)ka[3].x; tb[5] = (__bf16)ka[3].y;
            tb[6] = (__bf16)ka[3].z; tb[7] = (__bf16)ka[3].w;
            *(v8bf*)&k_lds[p][krow][kc0]     = ta;
            *(v8bf*)&k_lds[p][krow][kc0 + 8] = tb;
            for (int i2 = 0; i2 < 4; ++i2) {
                vT_lds[p][vd0 + 4 * i2 + 0][vcol] = (__bf16)va[i2].x;
                vT_lds[p][vd0 + 4 * i2 + 1][vcol] = (__bf16)va[i2].y;
                vT_lds[p][vd0 + 4 * i2 + 2][vcol] = (__bf16)va[i2].z;
                vT_lds[p][vd0 + 4 * i2 + 3][vcol] = (__bf16)va[i2].w;
            }
            for (int r2 = 0; r2 < 4; ++r2) kvs_cur[r2] = kvs_nxt[r2];
        };

        float l_acc[4];
        f32x4 o_acc[4];
        for (int r = 0; r < 4; ++r) l_acc[r] = 0.f;
        for (int t = 0; t < 4; ++t) o_acc[t] = (f32x4){0.f, 0.f, 0.f, 0.f};

        if (nt > 0) { issue(t0i); commit(0); }

        for (int i = 0; i < nt; ++i) {
            __syncthreads();                 // buf[i&1] ready for all waves
            const int p = i & 1;
            if (i + 1 < nt) issue(t0i + i + 1);   // hide global latency under compute

            const int tmin = __shfl(kvs_cur[0], 0);
            const int tmax = __shfl(kvs_cur[3], 15);
            if (!(tmax < wsmin || tmin > wsmax)) {
                // QK^T
                f32x4 s[4];
                __builtin_amdgcn_s_setprio(1);
                for (int n = 0; n < 4; ++n) {
                    s[n] = (f32x4){0.f, 0.f, 0.f, 0.f};
                    for (int c = 0; c < 2; ++c) {
                        v8bf kb = *(const v8bf*)&k_lds[p][n * 16 + l15][c * 32 + d_a];
                        s[n] = __builtin_amdgcn_mfma_f32_16x16x32_bf16(qfrag[c], kb, s[n], 0, 0, 0);
                    }
                }
                __builtin_amdgcn_s_setprio(0);
                // mask + exp2 vs fixed reference (shift-invariant softmax)
                for (int n = 0; n < 4; ++n)
                    for (int r = 0; r < 4; ++r) {
                        float sv = (kvs_cur[n] == qsegr[r]) ? s[n][r] : -__builtin_inff();
                        float pv = __builtin_amdgcn_exp2f(sv - M2REF);
                        l_acc[r] += pv;
                        p_lds[w][(lg << 2) + r][n * 16 + l15] = (__bf16)pv;
                    }
                // PV
                v8bf pa[2];
                for (int c = 0; c < 2; ++c)
                    pa[c] = *(const v8bf*)&p_lds[w][l15][c * 32 + d_a];
                __builtin_amdgcn_s_setprio(1);
                for (int t = 0; t < 4; ++t)
                    for (int c = 0; c < 2; ++c) {
                        v8bf vb = *(const v8bf*)&vT_lds[p][t * 16 + l15][c * 32 + d_a];
                        o_acc[t] = __builtin_amdgcn_mfma_f32_16x16x32_bf16(pa[c], vb, o_acc[t], 0, 0, 0);
                    }
                __builtin_amdgcn_s_setprio(0);
            }

            if (i + 1 < nt) commit((i + 1) & 1);  // vmcnt wait lands after compute
        }

        // ---- epilogue: reduce l across 16-lane column group, normalize
        float* outp = out + (((size_t)b * NH + h) * SQL) * DH;
        for (int r = 0; r < 4; ++r) {
            float x = l_acc[r];
            for (int d = 1; d < 16; d <<= 1) x += __shfl_xor(x, d);
            float inv = (x > 0.f) ? (1.f / x) : 0.f;
            for (int t = 0; t < 4; ++t)
                outp[(size_t)(qrow_c0 + r) * DH + t * 16 + l15] = o_acc[t][r] * inv;
        }

        __syncthreads();   // protect LDS (k/v/p) before next task restages
    }
}

extern "C" void kernel_launch(void* const* d_in, const int* in_sizes, int n_in,
                              void* d_out, int out_size, void* d_ws, size_t ws_size,
                              hipStream_t stream) {
    const float* q     = (const float*)d_in[0];
    const float* k     = (const float*)d_in[1];
    const float* v     = (const float*)d_in[2];
    const int*   qseg  = (const int*)d_in[3];
    const int*   kvseg = (const int*)d_in[4];
    float* out = (float*)d_out;
    unsigned* cnt = (unsigned*)d_ws;

    init_counter<<<dim3(1), dim3(64), 0, stream>>>(cnt);
    gqa_seg_attn<<<dim3(GRID), dim3(256), 0, stream>>>(q, k, v, qseg, kvseg, out, cnt);
}